// Round 6
// baseline (276.051 us; speedup 1.0000x reference)
//
#include <hip/hip_runtime.h>

#define S_ 512
#define R_ 128
#define C_ 256
#define H_ 8
#define DH_ 32
#define M_ (R_ * S_)  // 65536
#define EPS_ 1e-5f

typedef unsigned short u16;
typedef unsigned int u32;
typedef short bf16x8 __attribute__((ext_vector_type(8)));
typedef float f32x4 __attribute__((ext_vector_type(4)));

#define MFMA(a, b, c) __builtin_amdgcn_mfma_f32_16x16x32_bf16(a, b, c, 0, 0, 0)

// Pure-C RNE float->bf16 (no packing-order assumptions). Proven correct r5.
static __device__ inline u16 f2bf(float f) {
    union { float f; u32 u; } t;
    t.f = f;
    return (u16)((t.u + 0x7FFFu + ((t.u >> 16) & 1u)) >> 16);
}
static __device__ inline float bf2f(u16 v) {
    union { u32 u; float f; } t;
    t.u = ((u32)v) << 16;
    return t.f;
}

// ---------------- kernel 1: LN stats + normalize + bf16 + transpose --------
__global__ __launch_bounds__(256) void lnxn_kernel(const float* __restrict__ x,
                                                   const float* __restrict__ lnw,
                                                   const float* __restrict__ lnb,
                                                   u16* __restrict__ xnb) {
    int wave = threadIdx.x >> 6, lane = threadIdx.x & 63;
    int n = (blockIdx.x << 2) + wave;
    int r = n >> 9, s = n & (S_ - 1);
    const float4 v = ((const float4*)(x + (size_t)(s * R_ + r) * C_))[lane];
    float sum = v.x + v.y + v.z + v.w;
    float sq = v.x * v.x + v.y * v.y + v.z * v.z + v.w * v.w;
#pragma unroll
    for (int off = 32; off; off >>= 1) {
        sum += __shfl_xor(sum, off);
        sq += __shfl_xor(sq, off);
    }
    float mu = sum * (1.0f / C_);
    float rstd = rsqrtf(sq * (1.0f / C_) - mu * mu + EPS_);
    float4 w4 = ((const float4*)lnw)[lane];
    float4 b4 = ((const float4*)lnb)[lane];
    ushort4 st;
    st.x = f2bf((v.x - mu) * rstd * w4.x + b4.x);
    st.y = f2bf((v.y - mu) * rstd * w4.y + b4.y);
    st.z = f2bf((v.z - mu) * rstd * w4.z + b4.z);
    st.w = f2bf((v.w - mu) * rstd * w4.w + b4.w);
    *(ushort4*)(xnb + (size_t)n * C_ + lane * 4) = st;
}

// ---------------- kernel 2: weights -> bf16, transposed [n][k] -------------
__global__ __launch_bounds__(256) void wcvt_kernel(
    const float* __restrict__ wq, const float* __restrict__ wk,
    const float* __restrict__ wv, const float* __restrict__ wg,
    const float* __restrict__ wf, u16* __restrict__ wcat_t,
    u16* __restrict__ wf_t) {
    __shared__ __align__(16) float tile[32][33];
    const int z = blockIdx.z;
    const float* __restrict__ W =
        (z == 0) ? wq : (z == 1) ? wk : (z == 2) ? wv : (z == 3) ? wg : wf;
    u16* __restrict__ dst = (z < 4) ? (wcat_t + (size_t)z * C_ * C_) : wf_t;
    const int tid = threadIdx.x;
    int rk = tid >> 3, c4 = tid & 7;
    float4 t4 = *(const float4*)&W[(size_t)(blockIdx.x * 32 + rk) * C_ +
                                   blockIdx.y * 32 + c4 * 4];
    tile[rk][c4 * 4 + 0] = t4.x;
    tile[rk][c4 * 4 + 1] = t4.y;
    tile[rk][c4 * 4 + 2] = t4.z;
    tile[rk][c4 * 4 + 3] = t4.w;
    __syncthreads();
    int rn = tid >> 3, k4 = tid & 7;
    ushort4 st;
    st.x = f2bf(tile[k4 * 4 + 0][rn]);
    st.y = f2bf(tile[k4 * 4 + 1][rn]);
    st.z = f2bf(tile[k4 * 4 + 2][rn]);
    st.w = f2bf(tile[k4 * 4 + 3][rn]);
    *(ushort4*)(dst + (size_t)(blockIdx.y * 32 + rn) * C_ + blockIdx.x * 32 +
                k4 * 4) = st;
}

// ---------------- kernel 3: fused q/k/v/g projection GEMM (MFMA) -----------
// q scaled by log2(e)/sqrt(DH) (exp2 in attn); g sigmoid.
__global__ __launch_bounds__(256) void proj_kernel(
    const u16* __restrict__ xnb, const u16* __restrict__ wcat_t,
    const float* __restrict__ bg, u16* __restrict__ qb, u16* __restrict__ kb,
    u16* __restrict__ vb, u16* __restrict__ gb) {
    __shared__ __align__(16) u16 As[128 * 64];
    __shared__ __align__(16) u16 Bs[128 * 64];
    const int tid = threadIdx.x;
    const int l = tid & 63, wid = tid >> 6;
    const int g = l >> 4, ql = l & 15;
    const int wm = wid >> 1, wn = wid & 1;
    const int m0 = blockIdx.x << 7;
    const int n0 = blockIdx.y << 7;
    const int z = blockIdx.y >> 1;
    u16* __restrict__ O = (z == 0) ? qb : (z == 1) ? kb : (z == 2) ? vb : gb;

    const f32x4 zz = {0.f, 0.f, 0.f, 0.f};
    f32x4 acc[4][4];
#pragma unroll
    for (int i = 0; i < 4; ++i)
#pragma unroll
        for (int j = 0; j < 4; ++j) acc[i][j] = zz;

    for (int k0 = 0; k0 < C_; k0 += 64) {
        __syncthreads();
#pragma unroll
        for (int rep = 0; rep < 4; ++rep) {
            int idx = tid + rep * 256;
            int row = idx >> 3, c = idx & 7;
            *(uint4*)((char*)As + row * 128 + ((c * 16) ^ ((row & 7) << 4))) =
                *(const uint4*)(xnb + (size_t)(m0 + row) * C_ + k0 + c * 8);
            *(uint4*)((char*)Bs + row * 128 + ((c * 16) ^ ((row & 7) << 4))) =
                *(const uint4*)(wcat_t + (size_t)(n0 + row) * C_ + k0 + c * 8);
        }
        __syncthreads();
#pragma unroll
        for (int ks = 0; ks < 2; ++ks) {
            bf16x8 a[4], b[4];
#pragma unroll
            for (int mf = 0; mf < 4; ++mf) {
                int row = wm * 64 + mf * 16 + ql;
                a[mf] = *(const bf16x8*)((const char*)As + row * 128 +
                                         ((ks * 64 + g * 16) ^ ((row & 7) << 4)));
            }
#pragma unroll
            for (int nf = 0; nf < 4; ++nf) {
                int row = wn * 64 + nf * 16 + ql;
                b[nf] = *(const bf16x8*)((const char*)Bs + row * 128 +
                                         ((ks * 64 + g * 16) ^ ((row & 7) << 4)));
            }
#pragma unroll
            for (int mf = 0; mf < 4; ++mf)
#pragma unroll
                for (int nf = 0; nf < 4; ++nf)
                    acc[mf][nf] = MFMA(a[mf], b[nf], acc[mf][nf]);
        }
    }

#pragma unroll
    for (int nf = 0; nf < 4; ++nf) {
        int n_g = n0 + wn * 64 + nf * 16 + ql;
        int nz = n_g & 255;
        float bgv = (z == 3) ? bg[nz] : 0.0f;
#pragma unroll
        for (int mf = 0; mf < 4; ++mf) {
            int m = m0 + wm * 64 + mf * 16 + g * 4;
#pragma unroll
            for (int i = 0; i < 4; ++i) {
                float v = acc[mf][nf][i];
                // q: 1/sqrt(32) * log2(e) folded (attn uses exp2)
                if (z == 0) v *= 0.25505654003290507f;
                else if (z == 3) v = 1.0f / (1.0f + __expf(-(v + bgv)));
                O[(size_t)(m + i) * C_ + nz] = f2bf(v);
            }
        }
    }
}

// ---------------- kernel 4: attention v2 (in-register P, no LDS bounce) ----
// One block per (r,h): 8 waves x 64 q = all 512 q rows; K/V read ONCE.
// Swapped QK^T: S^T = K.Q^T; lane's own C/D regs form the PV B-fragment
// directly under the self-consistent k-slot map pi(g,j)=16*(j>=4)+g*4+(j&3).
// V^T A-fragment = two contiguous b64 reads from Vt[d][kv] at the same map.
__global__ __launch_bounds__(512) void attn_kernel(
    const u16* __restrict__ qb, const u16* __restrict__ kb,
    const u16* __restrict__ vb, const u16* __restrict__ gb,
    u16* __restrict__ ob) {
    __shared__ __align__(16) u16 Klds[64 * 40];  // [kv][d], row pad 80B
    __shared__ __align__(16) u16 Vt[32 * 72];    // [d][kv], row pad 144B
    const int rh = blockIdx.x;
    const int r = rh >> 3, h = rh & 7;
    const int tid = threadIdx.x;
    const int l = tid & 63, wid = tid >> 6;  // 8 waves
    const int g = l >> 4, ql = l & 15;
    const int mbase = r * S_ + wid * 64;
    const int hoff = h * DH_;
    const f32x4 zz = {0.f, 0.f, 0.f, 0.f};

    bf16x8 qf[4];
#pragma unroll
    for (int nf = 0; nf < 4; ++nf)
        qf[nf] = *(const bf16x8*)(qb + (size_t)(mbase + nf * 16 + ql) * C_ +
                                  hoff + g * 8);

    f32x4 o[2][4];
#pragma unroll
    for (int i = 0; i < 2; ++i)
#pragma unroll
        for (int j = 0; j < 4; ++j) o[i][j] = zz;
    float dsum[4] = {0.f, 0.f, 0.f, 0.f};

    for (int j0 = 0; j0 < S_; j0 += 64) {
        __syncthreads();
        {
            // 512 threads: thread -> (kv row, 4-d chunk). 8B loads.
            int row = tid >> 3, c = tid & 7;
            const size_t gsrc = (size_t)(r * S_ + j0 + row) * C_ + hoff + c * 4;
            *(uint2*)((char*)Klds + row * 80 + c * 8) = *(const uint2*)(kb + gsrc);
            uint2 vv = *(const uint2*)(vb + gsrc);
            Vt[(c * 4 + 0) * 72 + row] = (u16)(vv.x & 0xFFFFu);
            Vt[(c * 4 + 1) * 72 + row] = (u16)(vv.x >> 16);
            Vt[(c * 4 + 2) * 72 + row] = (u16)(vv.y & 0xFFFFu);
            Vt[(c * 4 + 3) * 72 + row] = (u16)(vv.y >> 16);
        }
        __syncthreads();
        bf16x8 kf[4];
#pragma unroll
        for (int mf = 0; mf < 4; ++mf)
            kf[mf] = *(const bf16x8*)((const char*)Klds + (mf * 16 + ql) * 80 +
                                      g * 16);
#pragma unroll
        for (int sub = 0; sub < 2; ++sub) {
            f32x4 s0[4], s1[4];
#pragma unroll
            for (int nf = 0; nf < 4; ++nf) {
                s0[nf] = MFMA(kf[sub * 2 + 0], qf[nf], zz);
                s1[nf] = MFMA(kf[sub * 2 + 1], qf[nf], zz);
            }
            // V^T fragment: k-slots (g,j): j<4 -> kv = sub*32+g*4+j,
            // j>=4 -> kv = sub*32+16+g*4+(j-4). Two contiguous b64 reads.
            bf16x8 vf[2];
#pragma unroll
            for (int mv = 0; mv < 2; ++mv) {
                union { bf16x8 v; uint2 u2[2]; } vu;
                const char* vrow = (const char*)Vt + (mv * 16 + ql) * 144;
                vu.u2[0] = *(const uint2*)(vrow + (sub * 32 + g * 4) * 2);
                vu.u2[1] = *(const uint2*)(vrow + (sub * 32 + 16 + g * 4) * 2);
                vf[mv] = vu.v;
            }
            // P^T fragment: lane's own exp2'd scores, in register order.
#pragma unroll
            for (int nf = 0; nf < 4; ++nf) {
                float e00 = exp2f(s0[nf][0]), e01 = exp2f(s0[nf][1]);
                float e02 = exp2f(s0[nf][2]), e03 = exp2f(s0[nf][3]);
                float e10 = exp2f(s1[nf][0]), e11 = exp2f(s1[nf][1]);
                float e12 = exp2f(s1[nf][2]), e13 = exp2f(s1[nf][3]);
                dsum[nf] += ((e00 + e01) + (e02 + e03)) +
                            ((e10 + e11) + (e12 + e13));
                union { bf16x8 v; u32 u[4]; } pu;
                pu.u[0] = (u32)f2bf(e00) | ((u32)f2bf(e01) << 16);
                pu.u[1] = (u32)f2bf(e02) | ((u32)f2bf(e03) << 16);
                pu.u[2] = (u32)f2bf(e10) | ((u32)f2bf(e11) << 16);
                pu.u[3] = (u32)f2bf(e12) | ((u32)f2bf(e13) << 16);
#pragma unroll
                for (int mv = 0; mv < 2; ++mv)
                    o[mv][nf] = MFMA(vf[mv], pu.v, o[mv][nf]);
            }
        }
    }

#pragma unroll
    for (int nf = 0; nf < 4; ++nf) {
        dsum[nf] += __shfl_xor(dsum[nf], 16);
        dsum[nf] += __shfl_xor(dsum[nf], 32);
    }
#pragma unroll
    for (int nf = 0; nf < 4; ++nf) {
        float inv = 1.0f / dsum[nf];
        size_t rowoff = (size_t)(mbase + nf * 16 + ql) * C_ + hoff;
#pragma unroll
        for (int mv = 0; mv < 2; ++mv) {
            size_t off = rowoff + mv * 16 + g * 4;
            const ushort4 gv = *(const ushort4*)(gb + off);
            ushort4 st;
            st.x = f2bf(o[mv][nf][0] * inv * bf2f(gv.x));
            st.y = f2bf(o[mv][nf][1] * inv * bf2f(gv.y));
            st.z = f2bf(o[mv][nf][2] * inv * bf2f(gv.z));
            st.w = f2bf(o[mv][nf][3] * inv * bf2f(gv.w));
            *(ushort4*)(ob + off) = st;
        }
    }
}

// ---------------- kernel 5: output projection + bias + transpose -----------
__global__ __launch_bounds__(256) void outproj_kernel(
    const u16* __restrict__ ob, const u16* __restrict__ wf_t,
    const float* __restrict__ bfb, float* __restrict__ out) {
    __shared__ __align__(16) u16 As[128 * 64];
    __shared__ __align__(16) u16 Bs[128 * 64];
    const int tid = threadIdx.x;
    const int l = tid & 63, wid = tid >> 6;
    const int g = l >> 4, ql = l & 15;
    const int wm = wid >> 1, wn = wid & 1;
    const int m0 = blockIdx.x << 7;
    const int n0 = blockIdx.y << 7;

    const f32x4 zz = {0.f, 0.f, 0.f, 0.f};
    f32x4 acc[4][4];
#pragma unroll
    for (int i = 0; i < 4; ++i)
#pragma unroll
        for (int j = 0; j < 4; ++j) acc[i][j] = zz;

    for (int k0 = 0; k0 < C_; k0 += 64) {
        __syncthreads();
#pragma unroll
        for (int rep = 0; rep < 4; ++rep) {
            int idx = tid + rep * 256;
            int row = idx >> 3, c = idx & 7;
            *(uint4*)((char*)As + row * 128 + ((c * 16) ^ ((row & 7) << 4))) =
                *(const uint4*)(ob + (size_t)(m0 + row) * C_ + k0 + c * 8);
            *(uint4*)((char*)Bs + row * 128 + ((c * 16) ^ ((row & 7) << 4))) =
                *(const uint4*)(wf_t + (size_t)(n0 + row) * C_ + k0 + c * 8);
        }
        __syncthreads();
#pragma unroll
        for (int ks = 0; ks < 2; ++ks) {
            bf16x8 a[4], b[4];
#pragma unroll
            for (int mf = 0; mf < 4; ++mf) {
                int row = wm * 64 + mf * 16 + ql;
                a[mf] = *(const bf16x8*)((const char*)As + row * 128 +
                                         ((ks * 64 + g * 16) ^ ((row & 7) << 4)));
            }
#pragma unroll
            for (int nf = 0; nf < 4; ++nf) {
                int row = wn * 64 + nf * 16 + ql;
                b[nf] = *(const bf16x8*)((const char*)Bs + row * 128 +
                                         ((ks * 64 + g * 16) ^ ((row & 7) << 4)));
            }
#pragma unroll
            for (int mf = 0; mf < 4; ++mf)
#pragma unroll
                for (int nf = 0; nf < 4; ++nf)
                    acc[mf][nf] = MFMA(a[mf], b[nf], acc[mf][nf]);
        }
    }

#pragma unroll
    for (int nf = 0; nf < 4; ++nf) {
        int n_g = n0 + wn * 64 + nf * 16 + ql;
        float bfv = bfb[n_g];
#pragma unroll
        for (int mf = 0; mf < 4; ++mf) {
            int m = m0 + wm * 64 + mf * 16 + g * 4;
#pragma unroll
            for (int i = 0; i < 4; ++i) {
                int mi = m + i;
                int r = mi >> 9, s = mi & (S_ - 1);
                out[(size_t)(s * R_ + r) * C_ + n_g] = acc[mf][nf][i] + bfv;
            }
        }
    }
}

extern "C" void kernel_launch(void* const* d_in, const int* in_sizes, int n_in,
                              void* d_out, int out_size, void* d_ws, size_t ws_size,
                              hipStream_t stream) {
    const float* x = (const float*)d_in[0];
    const float* lnw = (const float*)d_in[1];
    const float* lnb = (const float*)d_in[2];
    const float* wq = (const float*)d_in[3];
    const float* wk = (const float*)d_in[4];
    const float* wv = (const float*)d_in[5];
    const float* wg = (const float*)d_in[6];
    const float* bg = (const float*)d_in[7];
    const float* wf = (const float*)d_in[8];
    const float* bfb = (const float*)d_in[9];
    float* out = (float*)d_out;

    u16* ws = (u16*)d_ws;
    const size_t NC = (size_t)M_ * C_;  // 16,777,216 elems (32 MB as bf16)
    u16* xnb = ws;
    u16* wcat = xnb + NC;
    u16* wft = wcat + 1024 * 256;
    u16* qb = wft + 256 * 256;
    u16* kb = qb + NC;
    u16* vb = kb + NC;
    u16* gb = vb + NC;
    u16* obuf = gb + NC;
    // total: 6*NC + 327680 elems = ~193 MB (ws proven >= that in round 5)

    lnxn_kernel<<<M_ / 4, 256, 0, stream>>>(x, lnw, lnb, xnb);
    wcvt_kernel<<<dim3(8, 8, 5), 256, 0, stream>>>(wq, wk, wv, wg, wf, wcat, wft);
    proj_kernel<<<dim3(M_ / 128, 8), 256, 0, stream>>>(xnb, wcat, bg, qb, kb, vb, gb);
    attn_kernel<<<R_ * H_, 512, 0, stream>>>(qb, kb, vb, gb, obuf);
    outproj_kernel<<<dim3(M_ / 128, 2), 256, 0, stream>>>(obuf, wft, bfb, out);
}

// Round 7
// 222.960 us; speedup vs baseline: 1.2381x; 1.2381x over previous
//
#include <hip/hip_runtime.h>

#define S_ 512
#define R_ 128
#define C_ 256
#define H_ 8
#define DH_ 32
#define M_ (R_ * S_)  // 65536
#define EPS_ 1e-5f

typedef unsigned short u16;
typedef unsigned int u32;
typedef short bf16x8 __attribute__((ext_vector_type(8)));
typedef float f32x4 __attribute__((ext_vector_type(4)));

#define MFMA(a, b, c) __builtin_amdgcn_mfma_f32_16x16x32_bf16(a, b, c, 0, 0, 0)

// Pure-C RNE float->bf16 (no packing-order assumptions). Proven correct r5.
static __device__ inline u16 f2bf(float f) {
    union { float f; u32 u; } t;
    t.f = f;
    return (u16)((t.u + 0x7FFFu + ((t.u >> 16) & 1u)) >> 16);
}
static __device__ inline float bf2f(u16 v) {
    union { u32 u; float f; } t;
    t.u = ((u32)v) << 16;
    return t.f;
}
// Fast 2^x (raw v_exp_f32; log2e pre-folded into q scale by proj).
static __device__ inline float ex2(float x) {
    float r;
    asm("v_exp_f32 %0, %1" : "=v"(r) : "v"(x));
    return r;
}
// Truncation-pack two floats' high16 bits into one u32: [hi16(b)|hi16(a)].
// Byte-explicit (v_perm sel: 0-3 = S1 bytes, 4-7 = S0 bytes) -> no lo/hi
// semantics assumption. Used for P with dsum computed from the SAME
// truncated values, so quantization bias cancels in the softmax ratio.
static __device__ inline u32 packtrunc(float a, float b) {
    return __builtin_amdgcn_perm(__float_as_uint(b), __float_as_uint(a),
                                 0x07060302u);
}

// ---------------- kernel 1: LN stats + normalize + bf16 + transpose --------
__global__ __launch_bounds__(256) void lnxn_kernel(const float* __restrict__ x,
                                                   const float* __restrict__ lnw,
                                                   const float* __restrict__ lnb,
                                                   u16* __restrict__ xnb) {
    int wave = threadIdx.x >> 6, lane = threadIdx.x & 63;
    int n = (blockIdx.x << 2) + wave;
    int r = n >> 9, s = n & (S_ - 1);
    const float4 v = ((const float4*)(x + (size_t)(s * R_ + r) * C_))[lane];
    float sum = v.x + v.y + v.z + v.w;
    float sq = v.x * v.x + v.y * v.y + v.z * v.z + v.w * v.w;
#pragma unroll
    for (int off = 32; off; off >>= 1) {
        sum += __shfl_xor(sum, off);
        sq += __shfl_xor(sq, off);
    }
    float mu = sum * (1.0f / C_);
    float rstd = rsqrtf(sq * (1.0f / C_) - mu * mu + EPS_);
    float4 w4 = ((const float4*)lnw)[lane];
    float4 b4 = ((const float4*)lnb)[lane];
    ushort4 st;
    st.x = f2bf((v.x - mu) * rstd * w4.x + b4.x);
    st.y = f2bf((v.y - mu) * rstd * w4.y + b4.y);
    st.z = f2bf((v.z - mu) * rstd * w4.z + b4.z);
    st.w = f2bf((v.w - mu) * rstd * w4.w + b4.w);
    *(ushort4*)(xnb + (size_t)n * C_ + lane * 4) = st;
}

// ---------------- kernel 2: weights -> bf16, transposed [n][k] -------------
__global__ __launch_bounds__(256) void wcvt_kernel(
    const float* __restrict__ wq, const float* __restrict__ wk,
    const float* __restrict__ wv, const float* __restrict__ wg,
    const float* __restrict__ wf, u16* __restrict__ wcat_t,
    u16* __restrict__ wf_t) {
    __shared__ __align__(16) float tile[32][33];
    const int z = blockIdx.z;
    const float* __restrict__ W =
        (z == 0) ? wq : (z == 1) ? wk : (z == 2) ? wv : (z == 3) ? wg : wf;
    u16* __restrict__ dst = (z < 4) ? (wcat_t + (size_t)z * C_ * C_) : wf_t;
    const int tid = threadIdx.x;
    int rk = tid >> 3, c4 = tid & 7;
    float4 t4 = *(const float4*)&W[(size_t)(blockIdx.x * 32 + rk) * C_ +
                                   blockIdx.y * 32 + c4 * 4];
    tile[rk][c4 * 4 + 0] = t4.x;
    tile[rk][c4 * 4 + 1] = t4.y;
    tile[rk][c4 * 4 + 2] = t4.z;
    tile[rk][c4 * 4 + 3] = t4.w;
    __syncthreads();
    int rn = tid >> 3, k4 = tid & 7;
    ushort4 st;
    st.x = f2bf(tile[k4 * 4 + 0][rn]);
    st.y = f2bf(tile[k4 * 4 + 1][rn]);
    st.z = f2bf(tile[k4 * 4 + 2][rn]);
    st.w = f2bf(tile[k4 * 4 + 3][rn]);
    *(ushort4*)(dst + (size_t)(blockIdx.y * 32 + rn) * C_ + blockIdx.x * 32 +
                k4 * 4) = st;
}

// ---------------- kernel 3: fused q/k/v/g projection GEMM (MFMA) -----------
// q scaled by log2(e)/sqrt(DH) (v_exp in attn); g sigmoid.
__global__ __launch_bounds__(256) void proj_kernel(
    const u16* __restrict__ xnb, const u16* __restrict__ wcat_t,
    const float* __restrict__ bg, u16* __restrict__ qb, u16* __restrict__ kb,
    u16* __restrict__ vb, u16* __restrict__ gb) {
    __shared__ __align__(16) u16 As[128 * 64];
    __shared__ __align__(16) u16 Bs[128 * 64];
    const int tid = threadIdx.x;
    const int l = tid & 63, wid = tid >> 6;
    const int g = l >> 4, ql = l & 15;
    const int wm = wid >> 1, wn = wid & 1;
    const int m0 = blockIdx.x << 7;
    const int n0 = blockIdx.y << 7;
    const int z = blockIdx.y >> 1;
    u16* __restrict__ O = (z == 0) ? qb : (z == 1) ? kb : (z == 2) ? vb : gb;

    const f32x4 zz = {0.f, 0.f, 0.f, 0.f};
    f32x4 acc[4][4];
#pragma unroll
    for (int i = 0; i < 4; ++i)
#pragma unroll
        for (int j = 0; j < 4; ++j) acc[i][j] = zz;

    for (int k0 = 0; k0 < C_; k0 += 64) {
        __syncthreads();
#pragma unroll
        for (int rep = 0; rep < 4; ++rep) {
            int idx = tid + rep * 256;
            int row = idx >> 3, c = idx & 7;
            *(uint4*)((char*)As + row * 128 + ((c * 16) ^ ((row & 7) << 4))) =
                *(const uint4*)(xnb + (size_t)(m0 + row) * C_ + k0 + c * 8);
            *(uint4*)((char*)Bs + row * 128 + ((c * 16) ^ ((row & 7) << 4))) =
                *(const uint4*)(wcat_t + (size_t)(n0 + row) * C_ + k0 + c * 8);
        }
        __syncthreads();
#pragma unroll
        for (int ks = 0; ks < 2; ++ks) {
            bf16x8 a[4], b[4];
#pragma unroll
            for (int mf = 0; mf < 4; ++mf) {
                int row = wm * 64 + mf * 16 + ql;
                a[mf] = *(const bf16x8*)((const char*)As + row * 128 +
                                         ((ks * 64 + g * 16) ^ ((row & 7) << 4)));
            }
#pragma unroll
            for (int nf = 0; nf < 4; ++nf) {
                int row = wn * 64 + nf * 16 + ql;
                b[nf] = *(const bf16x8*)((const char*)Bs + row * 128 +
                                         ((ks * 64 + g * 16) ^ ((row & 7) << 4)));
            }
#pragma unroll
            for (int mf = 0; mf < 4; ++mf)
#pragma unroll
                for (int nf = 0; nf < 4; ++nf)
                    acc[mf][nf] = MFMA(a[mf], b[nf], acc[mf][nf]);
        }
    }

#pragma unroll
    for (int nf = 0; nf < 4; ++nf) {
        int n_g = n0 + wn * 64 + nf * 16 + ql;
        int nz = n_g & 255;
        float bgv = (z == 3) ? bg[nz] : 0.0f;
#pragma unroll
        for (int mf = 0; mf < 4; ++mf) {
            int m = m0 + wm * 64 + mf * 16 + g * 4;
#pragma unroll
            for (int i = 0; i < 4; ++i) {
                float v = acc[mf][nf][i];
                // q: 1/sqrt(32) * log2(e) folded (attn uses v_exp = 2^x)
                if (z == 0) v *= 0.25505654003290507f;
                else if (z == 3) v = 1.0f / (1.0f + __expf(-(v + bgv)));
                O[(size_t)(m + i) * C_ + nz] = f2bf(v);
            }
        }
    }
}

// ---------------- kernel 4: attention v3 --------------------------------
// 256 threads / 4 waves per (r,h,half); in-register P (self-consistent
// k-slot map pi(g,j)=16*(j>=4)+g*4+(j&3)); v_exp asm; trunc-pack P with
// dsum from the SAME truncated values (bias cancels in softmax ratio).
__global__ __launch_bounds__(256) void attn_kernel(
    const u16* __restrict__ qb, const u16* __restrict__ kb,
    const u16* __restrict__ vb, const u16* __restrict__ gb,
    u16* __restrict__ ob) {
    __shared__ __align__(16) u16 Klds[64 * 40];  // [kv][d], row pad 80B
    __shared__ __align__(16) u16 Vt[32 * 72];    // [d][kv], row pad 144B
    const int bid = blockIdx.x;
    const int rh = bid >> 1, half = bid & 1;
    const int r = rh >> 3, h = rh & 7;
    const int tid = threadIdx.x;
    const int l = tid & 63, wid = tid >> 6;
    const int g = l >> 4, ql = l & 15;
    const int mbase = r * S_ + half * 256 + wid * 64;
    const int hoff = h * DH_;
    const f32x4 zz = {0.f, 0.f, 0.f, 0.f};

    bf16x8 qf[4];
#pragma unroll
    for (int nf = 0; nf < 4; ++nf)
        qf[nf] = *(const bf16x8*)(qb + (size_t)(mbase + nf * 16 + ql) * C_ +
                                  hoff + g * 8);

    f32x4 o[2][4];
#pragma unroll
    for (int i = 0; i < 2; ++i)
#pragma unroll
        for (int j = 0; j < 4; ++j) o[i][j] = zz;
    float dsum[4] = {0.f, 0.f, 0.f, 0.f};

    for (int j0 = 0; j0 < S_; j0 += 64) {
        __syncthreads();
        {
            // 256 threads: (kv row, 16B d-chunk). K 16B load; V transpose.
            int row = tid >> 2, c = tid & 3;
            const size_t gsrc = (size_t)(r * S_ + j0 + row) * C_ + hoff + c * 8;
            *(uint4*)((char*)Klds + row * 80 + c * 16) = *(const uint4*)(kb + gsrc);
            bf16x8 vv = *(const bf16x8*)(vb + gsrc);
#pragma unroll
            for (int jj = 0; jj < 8; ++jj)
                Vt[(c * 8 + jj) * 72 + row] = (u16)vv[jj];
        }
        __syncthreads();
        bf16x8 kf[4];
#pragma unroll
        for (int mf = 0; mf < 4; ++mf)
            kf[mf] = *(const bf16x8*)((const char*)Klds + (mf * 16 + ql) * 80 +
                                      g * 16);
#pragma unroll
        for (int sub = 0; sub < 2; ++sub) {
            f32x4 s0[4], s1[4];
#pragma unroll
            for (int nf = 0; nf < 4; ++nf) {
                s0[nf] = MFMA(kf[sub * 2 + 0], qf[nf], zz);
                s1[nf] = MFMA(kf[sub * 2 + 1], qf[nf], zz);
            }
            // V^T fragment: k-slots (g,j): j<4 -> kv = sub*32+g*4+j,
            // j>=4 -> kv = sub*32+16+g*4+(j-4). Two contiguous b64 reads.
            bf16x8 vf[2];
#pragma unroll
            for (int mv = 0; mv < 2; ++mv) {
                union { bf16x8 v; uint2 u2[2]; } vu;
                const char* vrow = (const char*)Vt + (mv * 16 + ql) * 144;
                vu.u2[0] = *(const uint2*)(vrow + (sub * 32 + g * 4) * 2);
                vu.u2[1] = *(const uint2*)(vrow + (sub * 32 + 16 + g * 4) * 2);
                vf[mv] = vu.v;
            }
            // P^T fragment: lane's own 2^s scores, trunc-packed; dsum from
            // the truncated bf16 values themselves (bias-free softmax).
#pragma unroll
            for (int nf = 0; nf < 4; ++nf) {
                union { bf16x8 v; u32 u[4]; } pu;
                pu.u[0] = packtrunc(ex2(s0[nf][0]), ex2(s0[nf][1]));
                pu.u[1] = packtrunc(ex2(s0[nf][2]), ex2(s0[nf][3]));
                pu.u[2] = packtrunc(ex2(s1[nf][0]), ex2(s1[nf][1]));
                pu.u[3] = packtrunc(ex2(s1[nf][2]), ex2(s1[nf][3]));
                float ds = 0.f;
#pragma unroll
                for (int i = 0; i < 4; ++i) {
                    float lo = __uint_as_float(pu.u[i] << 16);
                    float hi = __uint_as_float(pu.u[i] & 0xFFFF0000u);
                    ds += lo + hi;
                }
                dsum[nf] += ds;
#pragma unroll
                for (int mv = 0; mv < 2; ++mv)
                    o[mv][nf] = MFMA(vf[mv], pu.v, o[mv][nf]);
            }
        }
    }

#pragma unroll
    for (int nf = 0; nf < 4; ++nf) {
        dsum[nf] += __shfl_xor(dsum[nf], 16);
        dsum[nf] += __shfl_xor(dsum[nf], 32);
    }
#pragma unroll
    for (int nf = 0; nf < 4; ++nf) {
        float inv = 1.0f / dsum[nf];
        size_t rowoff = (size_t)(mbase + nf * 16 + ql) * C_ + hoff;
#pragma unroll
        for (int mv = 0; mv < 2; ++mv) {
            size_t off = rowoff + mv * 16 + g * 4;
            const ushort4 gv = *(const ushort4*)(gb + off);
            ushort4 st;
            st.x = f2bf(o[mv][nf][0] * inv * bf2f(gv.x));
            st.y = f2bf(o[mv][nf][1] * inv * bf2f(gv.y));
            st.z = f2bf(o[mv][nf][2] * inv * bf2f(gv.z));
            st.w = f2bf(o[mv][nf][3] * inv * bf2f(gv.w));
            *(ushort4*)(ob + off) = st;
        }
    }
}

// ---------------- kernel 5: output projection + bias + transpose -----------
__global__ __launch_bounds__(256) void outproj_kernel(
    const u16* __restrict__ ob, const u16* __restrict__ wf_t,
    const float* __restrict__ bfb, float* __restrict__ out) {
    __shared__ __align__(16) u16 As[128 * 64];
    __shared__ __align__(16) u16 Bs[128 * 64];
    const int tid = threadIdx.x;
    const int l = tid & 63, wid = tid >> 6;
    const int g = l >> 4, ql = l & 15;
    const int wm = wid >> 1, wn = wid & 1;
    const int m0 = blockIdx.x << 7;
    const int n0 = blockIdx.y << 7;

    const f32x4 zz = {0.f, 0.f, 0.f, 0.f};
    f32x4 acc[4][4];
#pragma unroll
    for (int i = 0; i < 4; ++i)
#pragma unroll
        for (int j = 0; j < 4; ++j) acc[i][j] = zz;

    for (int k0 = 0; k0 < C_; k0 += 64) {
        __syncthreads();
#pragma unroll
        for (int rep = 0; rep < 4; ++rep) {
            int idx = tid + rep * 256;
            int row = idx >> 3, c = idx & 7;
            *(uint4*)((char*)As + row * 128 + ((c * 16) ^ ((row & 7) << 4))) =
                *(const uint4*)(ob + (size_t)(m0 + row) * C_ + k0 + c * 8);
            *(uint4*)((char*)Bs + row * 128 + ((c * 16) ^ ((row & 7) << 4))) =
                *(const uint4*)(wf_t + (size_t)(n0 + row) * C_ + k0 + c * 8);
        }
        __syncthreads();
#pragma unroll
        for (int ks = 0; ks < 2; ++ks) {
            bf16x8 a[4], b[4];
#pragma unroll
            for (int mf = 0; mf < 4; ++mf) {
                int row = wm * 64 + mf * 16 + ql;
                a[mf] = *(const bf16x8*)((const char*)As + row * 128 +
                                         ((ks * 64 + g * 16) ^ ((row & 7) << 4)));
            }
#pragma unroll
            for (int nf = 0; nf < 4; ++nf) {
                int row = wn * 64 + nf * 16 + ql;
                b[nf] = *(const bf16x8*)((const char*)Bs + row * 128 +
                                         ((ks * 64 + g * 16) ^ ((row & 7) << 4)));
            }
#pragma unroll
            for (int mf = 0; mf < 4; ++mf)
#pragma unroll
                for (int nf = 0; nf < 4; ++nf)
                    acc[mf][nf] = MFMA(a[mf], b[nf], acc[mf][nf]);
        }
    }

#pragma unroll
    for (int nf = 0; nf < 4; ++nf) {
        int n_g = n0 + wn * 64 + nf * 16 + ql;
        float bfv = bfb[n_g];
#pragma unroll
        for (int mf = 0; mf < 4; ++mf) {
            int m = m0 + wm * 64 + mf * 16 + g * 4;
#pragma unroll
            for (int i = 0; i < 4; ++i) {
                int mi = m + i;
                int r = mi >> 9, s = mi & (S_ - 1);
                out[(size_t)(s * R_ + r) * C_ + n_g] = acc[mf][nf][i] + bfv;
            }
        }
    }
}

extern "C" void kernel_launch(void* const* d_in, const int* in_sizes, int n_in,
                              void* d_out, int out_size, void* d_ws, size_t ws_size,
                              hipStream_t stream) {
    const float* x = (const float*)d_in[0];
    const float* lnw = (const float*)d_in[1];
    const float* lnb = (const float*)d_in[2];
    const float* wq = (const float*)d_in[3];
    const float* wk = (const float*)d_in[4];
    const float* wv = (const float*)d_in[5];
    const float* wg = (const float*)d_in[6];
    const float* bg = (const float*)d_in[7];
    const float* wf = (const float*)d_in[8];
    const float* bfb = (const float*)d_in[9];
    float* out = (float*)d_out;

    u16* ws = (u16*)d_ws;
    const size_t NC = (size_t)M_ * C_;  // 16,777,216 elems (32 MB as bf16)
    u16* xnb = ws;
    u16* wcat = xnb + NC;
    u16* wft = wcat + 1024 * 256;
    u16* qb = wft + 256 * 256;
    u16* kb = qb + NC;
    u16* vb = kb + NC;
    u16* gb = vb + NC;
    u16* obuf = gb + NC;
    // total: 6*NC + 327680 elems = ~193 MB (ws proven >= that in round 5)

    lnxn_kernel<<<M_ / 4, 256, 0, stream>>>(x, lnw, lnb, xnb);
    wcvt_kernel<<<dim3(8, 8, 5), 256, 0, stream>>>(wq, wk, wv, wg, wf, wcat, wft);
    proj_kernel<<<dim3(M_ / 128, 8), 256, 0, stream>>>(xnb, wcat, bg, qb, kb, vb, gb);
    attn_kernel<<<R_ * H_ * 2, 256, 0, stream>>>(qb, kb, vb, gb, obuf);
    outproj_kernel<<<dim3(M_ / 128, 2), 256, 0, stream>>>(obuf, wft, bfb, out);
}

// Round 8
// 215.392 us; speedup vs baseline: 1.2816x; 1.0351x over previous
//
#include <hip/hip_runtime.h>

#define S_ 512
#define R_ 128
#define C_ 256
#define H_ 8
#define DH_ 32
#define M_ (R_ * S_)  // 65536
#define EPS_ 1e-5f

typedef unsigned short u16;
typedef unsigned int u32;
typedef short bf16x8 __attribute__((ext_vector_type(8)));
typedef float f32x4 __attribute__((ext_vector_type(4)));

#define MFMA(a, b, c) __builtin_amdgcn_mfma_f32_16x16x32_bf16(a, b, c, 0, 0, 0)

// Pure-C RNE float->bf16 (no packing-order assumptions). Proven correct r5.
static __device__ inline u16 f2bf(float f) {
    union { float f; u32 u; } t;
    t.f = f;
    return (u16)((t.u + 0x7FFFu + ((t.u >> 16) & 1u)) >> 16);
}
static __device__ inline float bf2f(u16 v) {
    union { u32 u; float f; } t;
    t.u = ((u32)v) << 16;
    return t.f;
}
// Fast 2^x (raw v_exp_f32; log2e pre-folded into q scale by proj).
static __device__ inline float ex2(float x) {
    float r;
    asm("v_exp_f32 %0, %1" : "=v"(r) : "v"(x));
    return r;
}
// Truncation-pack two floats' high16 bits into one u32: [hi16(b)|hi16(a)].
static __device__ inline u32 packtrunc(float a, float b) {
    return __builtin_amdgcn_perm(__float_as_uint(b), __float_as_uint(a),
                                 0x07060302u);
}

// ---------------- kernel 1: LN stats + normalize + bf16 + transpose --------
__global__ __launch_bounds__(256) void lnxn_kernel(const float* __restrict__ x,
                                                   const float* __restrict__ lnw,
                                                   const float* __restrict__ lnb,
                                                   u16* __restrict__ xnb) {
    int wave = threadIdx.x >> 6, lane = threadIdx.x & 63;
    int n = (blockIdx.x << 2) + wave;
    int r = n >> 9, s = n & (S_ - 1);
    const float4 v = ((const float4*)(x + (size_t)(s * R_ + r) * C_))[lane];
    float sum = v.x + v.y + v.z + v.w;
    float sq = v.x * v.x + v.y * v.y + v.z * v.z + v.w * v.w;
#pragma unroll
    for (int off = 32; off; off >>= 1) {
        sum += __shfl_xor(sum, off);
        sq += __shfl_xor(sq, off);
    }
    float mu = sum * (1.0f / C_);
    float rstd = rsqrtf(sq * (1.0f / C_) - mu * mu + EPS_);
    float4 w4 = ((const float4*)lnw)[lane];
    float4 b4 = ((const float4*)lnb)[lane];
    ushort4 st;
    st.x = f2bf((v.x - mu) * rstd * w4.x + b4.x);
    st.y = f2bf((v.y - mu) * rstd * w4.y + b4.y);
    st.z = f2bf((v.z - mu) * rstd * w4.z + b4.z);
    st.w = f2bf((v.w - mu) * rstd * w4.w + b4.w);
    *(ushort4*)(xnb + (size_t)n * C_ + lane * 4) = st;
}

// ---------------- kernel 2: weights -> bf16, transposed [n][k] -------------
__global__ __launch_bounds__(256) void wcvt_kernel(
    const float* __restrict__ wq, const float* __restrict__ wk,
    const float* __restrict__ wv, const float* __restrict__ wg,
    const float* __restrict__ wf, u16* __restrict__ wcat_t,
    u16* __restrict__ wf_t) {
    __shared__ __align__(16) float tile[32][33];
    const int z = blockIdx.z;
    const float* __restrict__ W =
        (z == 0) ? wq : (z == 1) ? wk : (z == 2) ? wv : (z == 3) ? wg : wf;
    u16* __restrict__ dst = (z < 4) ? (wcat_t + (size_t)z * C_ * C_) : wf_t;
    const int tid = threadIdx.x;
    int rk = tid >> 3, c4 = tid & 7;
    float4 t4 = *(const float4*)&W[(size_t)(blockIdx.x * 32 + rk) * C_ +
                                   blockIdx.y * 32 + c4 * 4];
    tile[rk][c4 * 4 + 0] = t4.x;
    tile[rk][c4 * 4 + 1] = t4.y;
    tile[rk][c4 * 4 + 2] = t4.z;
    tile[rk][c4 * 4 + 3] = t4.w;
    __syncthreads();
    int rn = tid >> 3, k4 = tid & 7;
    ushort4 st;
    st.x = f2bf(tile[k4 * 4 + 0][rn]);
    st.y = f2bf(tile[k4 * 4 + 1][rn]);
    st.z = f2bf(tile[k4 * 4 + 2][rn]);
    st.w = f2bf(tile[k4 * 4 + 3][rn]);
    *(ushort4*)(dst + (size_t)(blockIdx.y * 32 + rn) * C_ + blockIdx.x * 32 +
                k4 * 4) = st;
}

// ---------------- kernel 3: fused q/k/v/g projection GEMM (MFMA) -----------
// Grid (8, 512): x = n-tile (A-sharing blocks temporally adjacent -> L3 hit),
// y = m-tile. Epilogue stages C-tile in LDS for fully-coalesced 16B writes.
__global__ __launch_bounds__(256) void proj_kernel(
    const u16* __restrict__ xnb, const u16* __restrict__ wcat_t,
    const float* __restrict__ bg, u16* __restrict__ qb, u16* __restrict__ kb,
    u16* __restrict__ vb, u16* __restrict__ gb) {
    __shared__ __align__(16) char smem[128 * 272];  // 34816 B
    u16* As = (u16*)smem;             // [128][64] swizzled, 16 KB
    u16* Bs = (u16*)(smem + 16384);   // [128][64] swizzled, 16 KB
    // epilogue reuses smem as Cs[128][136] u16 (pitch 272 B)

    const int tid = threadIdx.x;
    const int l = tid & 63, wid = tid >> 6;
    const int g = l >> 4, ql = l & 15;
    const int wm = wid >> 1, wn = wid & 1;
    const int n0 = blockIdx.x << 7;
    const int m0 = blockIdx.y << 7;
    const int z = blockIdx.x >> 1;
    u16* __restrict__ O = (z == 0) ? qb : (z == 1) ? kb : (z == 2) ? vb : gb;

    const f32x4 zz = {0.f, 0.f, 0.f, 0.f};
    f32x4 acc[4][4];
#pragma unroll
    for (int i = 0; i < 4; ++i)
#pragma unroll
        for (int j = 0; j < 4; ++j) acc[i][j] = zz;

    for (int k0 = 0; k0 < C_; k0 += 64) {
        __syncthreads();
#pragma unroll
        for (int rep = 0; rep < 4; ++rep) {
            int idx = tid + rep * 256;
            int row = idx >> 3, c = idx & 7;
            *(uint4*)((char*)As + row * 128 + ((c * 16) ^ ((row & 7) << 4))) =
                *(const uint4*)(xnb + (size_t)(m0 + row) * C_ + k0 + c * 8);
            *(uint4*)((char*)Bs + row * 128 + ((c * 16) ^ ((row & 7) << 4))) =
                *(const uint4*)(wcat_t + (size_t)(n0 + row) * C_ + k0 + c * 8);
        }
        __syncthreads();
#pragma unroll
        for (int ks = 0; ks < 2; ++ks) {
            bf16x8 a[4], b[4];
#pragma unroll
            for (int mf = 0; mf < 4; ++mf) {
                int row = wm * 64 + mf * 16 + ql;
                a[mf] = *(const bf16x8*)((const char*)As + row * 128 +
                                         ((ks * 64 + g * 16) ^ ((row & 7) << 4)));
            }
#pragma unroll
            for (int nf = 0; nf < 4; ++nf) {
                int row = wn * 64 + nf * 16 + ql;
                b[nf] = *(const bf16x8*)((const char*)Bs + row * 128 +
                                         ((ks * 64 + g * 16) ^ ((row & 7) << 4)));
            }
#pragma unroll
            for (int mf = 0; mf < 4; ++mf)
#pragma unroll
                for (int nf = 0; nf < 4; ++nf)
                    acc[mf][nf] = MFMA(a[mf], b[nf], acc[mf][nf]);
        }
    }

    // ---- epilogue: stage into LDS, then coalesced 16B global writes ----
    __syncthreads();  // all As/Bs reads complete before overwrite as Cs
    u16* Cs = (u16*)smem;  // [128][pitch 136]
#pragma unroll
    for (int nf = 0; nf < 4; ++nf) {
        int ncol = wn * 64 + nf * 16 + ql;  // 0..127 in tile
        float bgv = (z == 3) ? bg[(n0 + ncol) & 255] : 0.0f;
#pragma unroll
        for (int mf = 0; mf < 4; ++mf) {
            int mrow = wm * 64 + mf * 16 + g * 4;
#pragma unroll
            for (int i = 0; i < 4; ++i) {
                float v = acc[mf][nf][i];
                // q: 1/sqrt(32) * log2(e) folded (attn uses v_exp = 2^x)
                if (z == 0) v *= 0.25505654003290507f;
                else if (z == 3) v = 1.0f / (1.0f + __expf(-(v + bgv)));
                Cs[(mrow + i) * 136 + ncol] = f2bf(v);
            }
        }
    }
    __syncthreads();
    const int nz0 = (n0 & 255);
#pragma unroll
    for (int rep = 0; rep < 8; ++rep) {
        int idx = tid + rep * 256;
        int row = idx >> 4, c = idx & 15;
        *(uint4*)(O + (size_t)(m0 + row) * C_ + nz0 + c * 8) =
            *(const uint4*)((const char*)Cs + row * 272 + c * 16);
    }
}

// ---------------- kernel 4: attention v3 --------------------------------
// 256 threads / 4 waves per (r,h,half); in-register P (self-consistent
// k-slot map pi(g,j)=16*(j>=4)+g*4+(j&3)); v_exp asm; trunc-pack P with
// dsum from the SAME truncated values (bias cancels in softmax ratio).
__global__ __launch_bounds__(256) void attn_kernel(
    const u16* __restrict__ qb, const u16* __restrict__ kb,
    const u16* __restrict__ vb, const u16* __restrict__ gb,
    u16* __restrict__ ob) {
    __shared__ __align__(16) u16 Klds[64 * 40];  // [kv][d], row pad 80B
    __shared__ __align__(16) u16 Vt[32 * 72];    // [d][kv], row pad 144B
    const int bid = blockIdx.x;
    const int rh = bid >> 1, half = bid & 1;
    const int r = rh >> 3, h = rh & 7;
    const int tid = threadIdx.x;
    const int l = tid & 63, wid = tid >> 6;
    const int g = l >> 4, ql = l & 15;
    const int mbase = r * S_ + half * 256 + wid * 64;
    const int hoff = h * DH_;
    const f32x4 zz = {0.f, 0.f, 0.f, 0.f};

    bf16x8 qf[4];
#pragma unroll
    for (int nf = 0; nf < 4; ++nf)
        qf[nf] = *(const bf16x8*)(qb + (size_t)(mbase + nf * 16 + ql) * C_ +
                                  hoff + g * 8);

    f32x4 o[2][4];
#pragma unroll
    for (int i = 0; i < 2; ++i)
#pragma unroll
        for (int j = 0; j < 4; ++j) o[i][j] = zz;
    float dsum[4] = {0.f, 0.f, 0.f, 0.f};

    for (int j0 = 0; j0 < S_; j0 += 64) {
        __syncthreads();
        {
            // 256 threads: (kv row, 16B d-chunk). K 16B load; V transpose.
            int row = tid >> 2, c = tid & 3;
            const size_t gsrc = (size_t)(r * S_ + j0 + row) * C_ + hoff + c * 8;
            *(uint4*)((char*)Klds + row * 80 + c * 16) = *(const uint4*)(kb + gsrc);
            bf16x8 vv = *(const bf16x8*)(vb + gsrc);
#pragma unroll
            for (int jj = 0; jj < 8; ++jj)
                Vt[(c * 8 + jj) * 72 + row] = (u16)vv[jj];
        }
        __syncthreads();
        bf16x8 kf[4];
#pragma unroll
        for (int mf = 0; mf < 4; ++mf)
            kf[mf] = *(const bf16x8*)((const char*)Klds + (mf * 16 + ql) * 80 +
                                      g * 16);
#pragma unroll
        for (int sub = 0; sub < 2; ++sub) {
            f32x4 s0[4], s1[4];
#pragma unroll
            for (int nf = 0; nf < 4; ++nf) {
                s0[nf] = MFMA(kf[sub * 2 + 0], qf[nf], zz);
                s1[nf] = MFMA(kf[sub * 2 + 1], qf[nf], zz);
            }
            bf16x8 vf[2];
#pragma unroll
            for (int mv = 0; mv < 2; ++mv) {
                union { bf16x8 v; uint2 u2[2]; } vu;
                const char* vrow = (const char*)Vt + (mv * 16 + ql) * 144;
                vu.u2[0] = *(const uint2*)(vrow + (sub * 32 + g * 4) * 2);
                vu.u2[1] = *(const uint2*)(vrow + (sub * 32 + 16 + g * 4) * 2);
                vf[mv] = vu.v;
            }
#pragma unroll
            for (int nf = 0; nf < 4; ++nf) {
                union { bf16x8 v; u32 u[4]; } pu;
                pu.u[0] = packtrunc(ex2(s0[nf][0]), ex2(s0[nf][1]));
                pu.u[1] = packtrunc(ex2(s0[nf][2]), ex2(s0[nf][3]));
                pu.u[2] = packtrunc(ex2(s1[nf][0]), ex2(s1[nf][1]));
                pu.u[3] = packtrunc(ex2(s1[nf][2]), ex2(s1[nf][3]));
                float ds = 0.f;
#pragma unroll
                for (int i = 0; i < 4; ++i) {
                    float lo = __uint_as_float(pu.u[i] << 16);
                    float hi = __uint_as_float(pu.u[i] & 0xFFFF0000u);
                    ds += lo + hi;
                }
                dsum[nf] += ds;
#pragma unroll
                for (int mv = 0; mv < 2; ++mv)
                    o[mv][nf] = MFMA(vf[mv], pu.v, o[mv][nf]);
            }
        }
    }

#pragma unroll
    for (int nf = 0; nf < 4; ++nf) {
        dsum[nf] += __shfl_xor(dsum[nf], 16);
        dsum[nf] += __shfl_xor(dsum[nf], 32);
    }
#pragma unroll
    for (int nf = 0; nf < 4; ++nf) {
        float inv = 1.0f / dsum[nf];
        size_t rowoff = (size_t)(mbase + nf * 16 + ql) * C_ + hoff;
#pragma unroll
        for (int mv = 0; mv < 2; ++mv) {
            size_t off = rowoff + mv * 16 + g * 4;
            const ushort4 gv = *(const ushort4*)(gb + off);
            ushort4 st;
            st.x = f2bf(o[mv][nf][0] * inv * bf2f(gv.x));
            st.y = f2bf(o[mv][nf][1] * inv * bf2f(gv.y));
            st.z = f2bf(o[mv][nf][2] * inv * bf2f(gv.z));
            st.w = f2bf(o[mv][nf][3] * inv * bf2f(gv.w));
            *(ushort4*)(ob + off) = st;
        }
    }
}

// ---------------- kernel 5: output projection + bias + transpose -----------
__global__ __launch_bounds__(256) void outproj_kernel(
    const u16* __restrict__ ob, const u16* __restrict__ wf_t,
    const float* __restrict__ bfb, float* __restrict__ out) {
    __shared__ __align__(16) u16 As[128 * 64];
    __shared__ __align__(16) u16 Bs[128 * 64];
    const int tid = threadIdx.x;
    const int l = tid & 63, wid = tid >> 6;
    const int g = l >> 4, ql = l & 15;
    const int wm = wid >> 1, wn = wid & 1;
    const int m0 = blockIdx.x << 7;
    const int n0 = blockIdx.y << 7;

    const f32x4 zz = {0.f, 0.f, 0.f, 0.f};
    f32x4 acc[4][4];
#pragma unroll
    for (int i = 0; i < 4; ++i)
#pragma unroll
        for (int j = 0; j < 4; ++j) acc[i][j] = zz;

    for (int k0 = 0; k0 < C_; k0 += 64) {
        __syncthreads();
#pragma unroll
        for (int rep = 0; rep < 4; ++rep) {
            int idx = tid + rep * 256;
            int row = idx >> 3, c = idx & 7;
            *(uint4*)((char*)As + row * 128 + ((c * 16) ^ ((row & 7) << 4))) =
                *(const uint4*)(ob + (size_t)(m0 + row) * C_ + k0 + c * 8);
            *(uint4*)((char*)Bs + row * 128 + ((c * 16) ^ ((row & 7) << 4))) =
                *(const uint4*)(wf_t + (size_t)(n0 + row) * C_ + k0 + c * 8);
        }
        __syncthreads();
#pragma unroll
        for (int ks = 0; ks < 2; ++ks) {
            bf16x8 a[4], b[4];
#pragma unroll
            for (int mf = 0; mf < 4; ++mf) {
                int row = wm * 64 + mf * 16 + ql;
                a[mf] = *(const bf16x8*)((const char*)As + row * 128 +
                                         ((ks * 64 + g * 16) ^ ((row & 7) << 4)));
            }
#pragma unroll
            for (int nf = 0; nf < 4; ++nf) {
                int row = wn * 64 + nf * 16 + ql;
                b[nf] = *(const bf16x8*)((const char*)Bs + row * 128 +
                                         ((ks * 64 + g * 16) ^ ((row & 7) << 4)));
            }
#pragma unroll
            for (int mf = 0; mf < 4; ++mf)
#pragma unroll
                for (int nf = 0; nf < 4; ++nf)
                    acc[mf][nf] = MFMA(a[mf], b[nf], acc[mf][nf]);
        }
    }

#pragma unroll
    for (int nf = 0; nf < 4; ++nf) {
        int n_g = n0 + wn * 64 + nf * 16 + ql;
        float bfv = bfb[n_g];
#pragma unroll
        for (int mf = 0; mf < 4; ++mf) {
            int m = m0 + wm * 64 + mf * 16 + g * 4;
#pragma unroll
            for (int i = 0; i < 4; ++i) {
                int mi = m + i;
                int r = mi >> 9, s = mi & (S_ - 1);
                out[(size_t)(s * R_ + r) * C_ + n_g] = acc[mf][nf][i] + bfv;
            }
        }
    }
}

extern "C" void kernel_launch(void* const* d_in, const int* in_sizes, int n_in,
                              void* d_out, int out_size, void* d_ws, size_t ws_size,
                              hipStream_t stream) {
    const float* x = (const float*)d_in[0];
    const float* lnw = (const float*)d_in[1];
    const float* lnb = (const float*)d_in[2];
    const float* wq = (const float*)d_in[3];
    const float* wk = (const float*)d_in[4];
    const float* wv = (const float*)d_in[5];
    const float* wg = (const float*)d_in[6];
    const float* bg = (const float*)d_in[7];
    const float* wf = (const float*)d_in[8];
    const float* bfb = (const float*)d_in[9];
    float* out = (float*)d_out;

    u16* ws = (u16*)d_ws;
    const size_t NC = (size_t)M_ * C_;  // 16,777,216 elems (32 MB as bf16)
    u16* xnb = ws;
    u16* wcat = xnb + NC;
    u16* wft = wcat + 1024 * 256;
    u16* qb = wft + 256 * 256;
    u16* kb = qb + NC;
    u16* vb = kb + NC;
    u16* gb = vb + NC;
    u16* obuf = gb + NC;
    // total: 6*NC + 327680 elems = ~193 MB (ws proven >= that in round 5)

    lnxn_kernel<<<M_ / 4, 256, 0, stream>>>(x, lnw, lnb, xnb);
    wcvt_kernel<<<dim3(8, 8, 5), 256, 0, stream>>>(wq, wk, wv, wg, wf, wcat, wft);
    proj_kernel<<<dim3(8, M_ / 128), 256, 0, stream>>>(xnb, wcat, bg, qb, kb, vb, gb);
    attn_kernel<<<R_ * H_ * 2, 256, 0, stream>>>(qb, kb, vb, gb, obuf);
    outproj_kernel<<<dim3(M_ / 128, 2), 256, 0, stream>>>(obuf, wft, bfb, out);
}

// Round 9
// 193.413 us; speedup vs baseline: 1.4273x; 1.1136x over previous
//
#include <hip/hip_runtime.h>

#define S_ 512
#define R_ 128
#define C_ 256
#define H_ 8
#define DH_ 32
#define M_ (R_ * S_)  // 65536
#define EPS_ 1e-5f

typedef unsigned short u16;
typedef unsigned int u32;
typedef short bf16x8 __attribute__((ext_vector_type(8)));
typedef float f32x4 __attribute__((ext_vector_type(4)));

#define MFMA(a, b, c) __builtin_amdgcn_mfma_f32_16x16x32_bf16(a, b, c, 0, 0, 0)

// Pure-C RNE float->bf16 (no packing-order assumptions). Proven correct r5.
static __device__ inline u16 f2bf(float f) {
    union { float f; u32 u; } t;
    t.f = f;
    return (u16)((t.u + 0x7FFFu + ((t.u >> 16) & 1u)) >> 16);
}
static __device__ inline float bf2f(u16 v) {
    union { u32 u; float f; } t;
    t.u = ((u32)v) << 16;
    return t.f;
}
// Fast 2^x (raw v_exp_f32; log2e pre-folded into q scale by proj).
static __device__ inline float ex2(float x) {
    float r;
    asm("v_exp_f32 %0, %1" : "=v"(r) : "v"(x));
    return r;
}
// Truncation-pack two floats' high16 bits into one u32: [hi16(b)|hi16(a)].
static __device__ inline u32 packtrunc(float a, float b) {
    return __builtin_amdgcn_perm(__float_as_uint(b), __float_as_uint(a),
                                 0x07060302u);
}

// ---------------- kernel 1: LN stats + normalize + bf16 + transpose --------
__global__ __launch_bounds__(256) void lnxn_kernel(const float* __restrict__ x,
                                                   const float* __restrict__ lnw,
                                                   const float* __restrict__ lnb,
                                                   u16* __restrict__ xnb) {
    int wave = threadIdx.x >> 6, lane = threadIdx.x & 63;
    int n = (blockIdx.x << 2) + wave;
    int r = n >> 9, s = n & (S_ - 1);
    const float4 v = ((const float4*)(x + (size_t)(s * R_ + r) * C_))[lane];
    float sum = v.x + v.y + v.z + v.w;
    float sq = v.x * v.x + v.y * v.y + v.z * v.z + v.w * v.w;
#pragma unroll
    for (int off = 32; off; off >>= 1) {
        sum += __shfl_xor(sum, off);
        sq += __shfl_xor(sq, off);
    }
    float mu = sum * (1.0f / C_);
    float rstd = rsqrtf(sq * (1.0f / C_) - mu * mu + EPS_);
    float4 w4 = ((const float4*)lnw)[lane];
    float4 b4 = ((const float4*)lnb)[lane];
    ushort4 st;
    st.x = f2bf((v.x - mu) * rstd * w4.x + b4.x);
    st.y = f2bf((v.y - mu) * rstd * w4.y + b4.y);
    st.z = f2bf((v.z - mu) * rstd * w4.z + b4.z);
    st.w = f2bf((v.w - mu) * rstd * w4.w + b4.w);
    *(ushort4*)(xnb + (size_t)n * C_ + lane * 4) = st;
}

// ---------------- kernel 2: weights -> bf16, transposed [n][k] -------------
__global__ __launch_bounds__(256) void wcvt_kernel(
    const float* __restrict__ wq, const float* __restrict__ wk,
    const float* __restrict__ wv, const float* __restrict__ wg,
    const float* __restrict__ wf, u16* __restrict__ wcat_t,
    u16* __restrict__ wf_t) {
    __shared__ __align__(16) float tile[32][33];
    const int z = blockIdx.z;
    const float* __restrict__ W =
        (z == 0) ? wq : (z == 1) ? wk : (z == 2) ? wv : (z == 3) ? wg : wf;
    u16* __restrict__ dst = (z < 4) ? (wcat_t + (size_t)z * C_ * C_) : wf_t;
    const int tid = threadIdx.x;
    int rk = tid >> 3, c4 = tid & 7;
    float4 t4 = *(const float4*)&W[(size_t)(blockIdx.x * 32 + rk) * C_ +
                                   blockIdx.y * 32 + c4 * 4];
    tile[rk][c4 * 4 + 0] = t4.x;
    tile[rk][c4 * 4 + 1] = t4.y;
    tile[rk][c4 * 4 + 2] = t4.z;
    tile[rk][c4 * 4 + 3] = t4.w;
    __syncthreads();
    int rn = tid >> 3, k4 = tid & 7;
    ushort4 st;
    st.x = f2bf(tile[k4 * 4 + 0][rn]);
    st.y = f2bf(tile[k4 * 4 + 1][rn]);
    st.z = f2bf(tile[k4 * 4 + 2][rn]);
    st.w = f2bf(tile[k4 * 4 + 3][rn]);
    *(ushort4*)(dst + (size_t)(blockIdx.y * 32 + rn) * C_ + blockIdx.x * 32 +
                k4 * 4) = st;
}

// ---------------- kernel 3: fused q/k/v/g projection GEMM (MFMA) -----------
// 1D grid 4096, XCD-aware decode: the 8 n-tile blocks sharing one A-tile get
// ids congruent mod 8 -> same XCD L2 -> A fetched from HBM once.
__global__ __launch_bounds__(256) void proj_kernel(
    const u16* __restrict__ xnb, const u16* __restrict__ wcat_t,
    const float* __restrict__ bg, u16* __restrict__ qb, u16* __restrict__ kb,
    u16* __restrict__ vb, u16* __restrict__ gb) {
    __shared__ __align__(16) char smem[128 * 272];  // 34816 B
    u16* As = (u16*)smem;             // [128][64] swizzled, 16 KB
    u16* Bs = (u16*)(smem + 16384);   // [128][64] swizzled, 16 KB
    // epilogue reuses smem as Cs[128][136] u16 (pitch 272 B)

    const int tid = threadIdx.x;
    const int l = tid & 63, wid = tid >> 6;
    const int g = l >> 4, ql = l & 15;
    const int wm = wid >> 1, wn = wid & 1;
    // XCD-aware bijective decode (assumes XCD = linear id % 8, perf-only)
    const int id = blockIdx.x;
    const int xcd = id & 7, j = id >> 3;
    const int ntile = j & 7;
    const int mtile = (j >> 3) * 8 + xcd;  // 0..511, all 8 ntiles same xcd
    const int n0 = ntile << 7;
    const int m0 = mtile << 7;
    const int z = ntile >> 1;
    u16* __restrict__ O = (z == 0) ? qb : (z == 1) ? kb : (z == 2) ? vb : gb;

    const f32x4 zz = {0.f, 0.f, 0.f, 0.f};
    f32x4 acc[4][4];
#pragma unroll
    for (int i = 0; i < 4; ++i)
#pragma unroll
        for (int j2 = 0; j2 < 4; ++j2) acc[i][j2] = zz;

    for (int k0 = 0; k0 < C_; k0 += 64) {
        __syncthreads();
#pragma unroll
        for (int rep = 0; rep < 4; ++rep) {
            int idx = tid + rep * 256;
            int row = idx >> 3, c = idx & 7;
            *(uint4*)((char*)As + row * 128 + ((c * 16) ^ ((row & 7) << 4))) =
                *(const uint4*)(xnb + (size_t)(m0 + row) * C_ + k0 + c * 8);
            *(uint4*)((char*)Bs + row * 128 + ((c * 16) ^ ((row & 7) << 4))) =
                *(const uint4*)(wcat_t + (size_t)(n0 + row) * C_ + k0 + c * 8);
        }
        __syncthreads();
#pragma unroll
        for (int ks = 0; ks < 2; ++ks) {
            bf16x8 a[4], b[4];
#pragma unroll
            for (int mf = 0; mf < 4; ++mf) {
                int row = wm * 64 + mf * 16 + ql;
                a[mf] = *(const bf16x8*)((const char*)As + row * 128 +
                                         ((ks * 64 + g * 16) ^ ((row & 7) << 4)));
            }
#pragma unroll
            for (int nf = 0; nf < 4; ++nf) {
                int row = wn * 64 + nf * 16 + ql;
                b[nf] = *(const bf16x8*)((const char*)Bs + row * 128 +
                                         ((ks * 64 + g * 16) ^ ((row & 7) << 4)));
            }
#pragma unroll
            for (int mf = 0; mf < 4; ++mf)
#pragma unroll
                for (int nf = 0; nf < 4; ++nf)
                    acc[mf][nf] = MFMA(a[mf], b[nf], acc[mf][nf]);
        }
    }

    // ---- epilogue: stage into LDS, then coalesced 16B global writes ----
    __syncthreads();  // all As/Bs reads complete before overwrite as Cs
    u16* Cs = (u16*)smem;  // [128][pitch 136]
#pragma unroll
    for (int nf = 0; nf < 4; ++nf) {
        int ncol = wn * 64 + nf * 16 + ql;  // 0..127 in tile
        float bgv = (z == 3) ? bg[(n0 + ncol) & 255] : 0.0f;
#pragma unroll
        for (int mf = 0; mf < 4; ++mf) {
            int mrow = wm * 64 + mf * 16 + g * 4;
#pragma unroll
            for (int i = 0; i < 4; ++i) {
                float v = acc[mf][nf][i];
                // q: 1/sqrt(32) * log2(e) folded (attn uses v_exp = 2^x)
                if (z == 0) v *= 0.25505654003290507f;
                else if (z == 3) v = 1.0f / (1.0f + __expf(-(v + bgv)));
                Cs[(mrow + i) * 136 + ncol] = f2bf(v);
            }
        }
    }
    __syncthreads();
    const int nz0 = (n0 & 255);
#pragma unroll
    for (int rep = 0; rep < 8; ++rep) {
        int idx = tid + rep * 256;
        int row = idx >> 4, c = idx & 15;
        *(uint4*)(O + (size_t)(m0 + row) * C_ + nz0 + c * 8) =
            *(const uint4*)((const char*)Cs + row * 272 + c * 16);
    }
}

// ---------------- kernel 4: attention v3 (XCD-paired halves) ---------------
// 256 threads / 4 waves per (r,h,half); in-register P (self-consistent
// k-slot map pi(g,j)=16*(j>=4)+g*4+(j&3)); v_exp asm; trunc-pack P with
// dsum from the SAME truncated values. Halves sharing K/V -> same XCD.
__global__ __launch_bounds__(256) void attn_kernel(
    const u16* __restrict__ qb, const u16* __restrict__ kb,
    const u16* __restrict__ vb, const u16* __restrict__ gb,
    u16* __restrict__ ob) {
    __shared__ __align__(16) u16 Klds[64 * 40];  // [kv][d], row pad 80B
    __shared__ __align__(16) u16 Vt[32 * 72];    // [d][kv], row pad 144B
    const int id = blockIdx.x;
    const int xcd = id & 7, j = id >> 3;
    const int half = j & 1;
    const int rh = (j >> 1) * 8 + xcd;  // 0..1023; both halves same xcd
    const int r = rh >> 3, h = rh & 7;
    const int tid = threadIdx.x;
    const int l = tid & 63, wid = tid >> 6;
    const int g = l >> 4, ql = l & 15;
    const int mbase = r * S_ + half * 256 + wid * 64;
    const int hoff = h * DH_;
    const f32x4 zz = {0.f, 0.f, 0.f, 0.f};

    bf16x8 qf[4];
#pragma unroll
    for (int nf = 0; nf < 4; ++nf)
        qf[nf] = *(const bf16x8*)(qb + (size_t)(mbase + nf * 16 + ql) * C_ +
                                  hoff + g * 8);

    f32x4 o[2][4];
#pragma unroll
    for (int i = 0; i < 2; ++i)
#pragma unroll
        for (int j2 = 0; j2 < 4; ++j2) o[i][j2] = zz;
    float dsum[4] = {0.f, 0.f, 0.f, 0.f};

    for (int j0 = 0; j0 < S_; j0 += 64) {
        __syncthreads();
        {
            // 256 threads: (kv row, 16B d-chunk). K 16B load; V transpose.
            int row = tid >> 2, c = tid & 3;
            const size_t gsrc = (size_t)(r * S_ + j0 + row) * C_ + hoff + c * 8;
            *(uint4*)((char*)Klds + row * 80 + c * 16) = *(const uint4*)(kb + gsrc);
            bf16x8 vv = *(const bf16x8*)(vb + gsrc);
#pragma unroll
            for (int jj = 0; jj < 8; ++jj)
                Vt[(c * 8 + jj) * 72 + row] = (u16)vv[jj];
        }
        __syncthreads();
        bf16x8 kf[4];
#pragma unroll
        for (int mf = 0; mf < 4; ++mf)
            kf[mf] = *(const bf16x8*)((const char*)Klds + (mf * 16 + ql) * 80 +
                                      g * 16);
#pragma unroll
        for (int sub = 0; sub < 2; ++sub) {
            f32x4 s0[4], s1[4];
#pragma unroll
            for (int nf = 0; nf < 4; ++nf) {
                s0[nf] = MFMA(kf[sub * 2 + 0], qf[nf], zz);
                s1[nf] = MFMA(kf[sub * 2 + 1], qf[nf], zz);
            }
            bf16x8 vf[2];
#pragma unroll
            for (int mv = 0; mv < 2; ++mv) {
                union { bf16x8 v; uint2 u2[2]; } vu;
                const char* vrow = (const char*)Vt + (mv * 16 + ql) * 144;
                vu.u2[0] = *(const uint2*)(vrow + (sub * 32 + g * 4) * 2);
                vu.u2[1] = *(const uint2*)(vrow + (sub * 32 + 16 + g * 4) * 2);
                vf[mv] = vu.v;
            }
#pragma unroll
            for (int nf = 0; nf < 4; ++nf) {
                union { bf16x8 v; u32 u[4]; } pu;
                pu.u[0] = packtrunc(ex2(s0[nf][0]), ex2(s0[nf][1]));
                pu.u[1] = packtrunc(ex2(s0[nf][2]), ex2(s0[nf][3]));
                pu.u[2] = packtrunc(ex2(s1[nf][0]), ex2(s1[nf][1]));
                pu.u[3] = packtrunc(ex2(s1[nf][2]), ex2(s1[nf][3]));
                float ds = 0.f;
#pragma unroll
                for (int i = 0; i < 4; ++i) {
                    float lo = __uint_as_float(pu.u[i] << 16);
                    float hi = __uint_as_float(pu.u[i] & 0xFFFF0000u);
                    ds += lo + hi;
                }
                dsum[nf] += ds;
#pragma unroll
                for (int mv = 0; mv < 2; ++mv)
                    o[mv][nf] = MFMA(vf[mv], pu.v, o[mv][nf]);
            }
        }
    }

#pragma unroll
    for (int nf = 0; nf < 4; ++nf) {
        dsum[nf] += __shfl_xor(dsum[nf], 16);
        dsum[nf] += __shfl_xor(dsum[nf], 32);
    }
#pragma unroll
    for (int nf = 0; nf < 4; ++nf) {
        float inv = 1.0f / dsum[nf];
        size_t rowoff = (size_t)(mbase + nf * 16 + ql) * C_ + hoff;
#pragma unroll
        for (int mv = 0; mv < 2; ++mv) {
            size_t off = rowoff + mv * 16 + g * 4;
            const ushort4 gv = *(const ushort4*)(gb + off);
            ushort4 st;
            st.x = f2bf(o[mv][nf][0] * inv * bf2f(gv.x));
            st.y = f2bf(o[mv][nf][1] * inv * bf2f(gv.y));
            st.z = f2bf(o[mv][nf][2] * inv * bf2f(gv.z));
            st.w = f2bf(o[mv][nf][3] * inv * bf2f(gv.w));
            *(ushort4*)(ob + off) = st;
        }
    }
}

// ---------------- kernel 5: output projection + bias + transpose -----------
// 1D grid 1024, XCD-aware: both n-tiles sharing an A-tile -> same XCD.
__global__ __launch_bounds__(256) void outproj_kernel(
    const u16* __restrict__ ob, const u16* __restrict__ wf_t,
    const float* __restrict__ bfb, float* __restrict__ out) {
    __shared__ __align__(16) u16 As[128 * 64];
    __shared__ __align__(16) u16 Bs[128 * 64];
    const int tid = threadIdx.x;
    const int l = tid & 63, wid = tid >> 6;
    const int g = l >> 4, ql = l & 15;
    const int wm = wid >> 1, wn = wid & 1;
    const int id = blockIdx.x;
    const int xcd = id & 7, j = id >> 3;
    const int ntile = j & 1;
    const int mtile = (j >> 1) * 8 + xcd;  // 0..511
    const int m0 = mtile << 7;
    const int n0 = ntile << 7;

    const f32x4 zz = {0.f, 0.f, 0.f, 0.f};
    f32x4 acc[4][4];
#pragma unroll
    for (int i = 0; i < 4; ++i)
#pragma unroll
        for (int j2 = 0; j2 < 4; ++j2) acc[i][j2] = zz;

    for (int k0 = 0; k0 < C_; k0 += 64) {
        __syncthreads();
#pragma unroll
        for (int rep = 0; rep < 4; ++rep) {
            int idx = tid + rep * 256;
            int row = idx >> 3, c = idx & 7;
            *(uint4*)((char*)As + row * 128 + ((c * 16) ^ ((row & 7) << 4))) =
                *(const uint4*)(ob + (size_t)(m0 + row) * C_ + k0 + c * 8);
            *(uint4*)((char*)Bs + row * 128 + ((c * 16) ^ ((row & 7) << 4))) =
                *(const uint4*)(wf_t + (size_t)(n0 + row) * C_ + k0 + c * 8);
        }
        __syncthreads();
#pragma unroll
        for (int ks = 0; ks < 2; ++ks) {
            bf16x8 a[4], b[4];
#pragma unroll
            for (int mf = 0; mf < 4; ++mf) {
                int row = wm * 64 + mf * 16 + ql;
                a[mf] = *(const bf16x8*)((const char*)As + row * 128 +
                                         ((ks * 64 + g * 16) ^ ((row & 7) << 4)));
            }
#pragma unroll
            for (int nf = 0; nf < 4; ++nf) {
                int row = wn * 64 + nf * 16 + ql;
                b[nf] = *(const bf16x8*)((const char*)Bs + row * 128 +
                                         ((ks * 64 + g * 16) ^ ((row & 7) << 4)));
            }
#pragma unroll
            for (int mf = 0; mf < 4; ++mf)
#pragma unroll
                for (int nf = 0; nf < 4; ++nf)
                    acc[mf][nf] = MFMA(a[mf], b[nf], acc[mf][nf]);
        }
    }

#pragma unroll
    for (int nf = 0; nf < 4; ++nf) {
        int n_g = n0 + wn * 64 + nf * 16 + ql;
        float bfv = bfb[n_g];
#pragma unroll
        for (int mf = 0; mf < 4; ++mf) {
            int m = m0 + wm * 64 + mf * 16 + g * 4;
#pragma unroll
            for (int i = 0; i < 4; ++i) {
                int mi = m + i;
                int r = mi >> 9, s = mi & (S_ - 1);
                out[(size_t)(s * R_ + r) * C_ + n_g] = acc[mf][nf][i] + bfv;
            }
        }
    }
}

extern "C" void kernel_launch(void* const* d_in, const int* in_sizes, int n_in,
                              void* d_out, int out_size, void* d_ws, size_t ws_size,
                              hipStream_t stream) {
    const float* x = (const float*)d_in[0];
    const float* lnw = (const float*)d_in[1];
    const float* lnb = (const float*)d_in[2];
    const float* wq = (const float*)d_in[3];
    const float* wk = (const float*)d_in[4];
    const float* wv = (const float*)d_in[5];
    const float* wg = (const float*)d_in[6];
    const float* bg = (const float*)d_in[7];
    const float* wf = (const float*)d_in[8];
    const float* bfb = (const float*)d_in[9];
    float* out = (float*)d_out;

    u16* ws = (u16*)d_ws;
    const size_t NC = (size_t)M_ * C_;  // 16,777,216 elems (32 MB as bf16)
    u16* xnb = ws;
    u16* wcat = xnb + NC;
    u16* wft = wcat + 1024 * 256;
    u16* qb = wft + 256 * 256;
    u16* kb = qb + NC;
    u16* vb = kb + NC;
    u16* gb = vb + NC;
    u16* obuf = gb + NC;
    // total: 6*NC + 327680 elems = ~193 MB (ws proven >= that in round 5)

    lnxn_kernel<<<M_ / 4, 256, 0, stream>>>(x, lnw, lnb, xnb);
    wcvt_kernel<<<dim3(8, 8, 5), 256, 0, stream>>>(wq, wk, wv, wg, wf, wcat, wft);
    proj_kernel<<<4096, 256, 0, stream>>>(xnb, wcat, bg, qb, kb, vb, gb);
    attn_kernel<<<2048, 256, 0, stream>>>(qb, kb, vb, gb, obuf);
    outproj_kernel<<<1024, 256, 0, stream>>>(obuf, wft, bfb, out);
}

// Round 10
// 186.724 us; speedup vs baseline: 1.4784x; 1.0358x over previous
//
#include <hip/hip_runtime.h>

#define S_ 512
#define R_ 128
#define C_ 256
#define H_ 8
#define DH_ 32
#define M_ (R_ * S_)  // 65536
#define EPS_ 1e-5f

typedef unsigned short u16;
typedef unsigned int u32;
typedef short bf16x8 __attribute__((ext_vector_type(8)));
typedef float f32x4 __attribute__((ext_vector_type(4)));

#define MFMA(a, b, c) __builtin_amdgcn_mfma_f32_16x16x32_bf16(a, b, c, 0, 0, 0)

// Pure-C RNE float->bf16 (no packing-order assumptions). Proven correct r5.
static __device__ inline u16 f2bf(float f) {
    union { float f; u32 u; } t;
    t.f = f;
    return (u16)((t.u + 0x7FFFu + ((t.u >> 16) & 1u)) >> 16);
}
static __device__ inline float bf2f(u16 v) {
    union { u32 u; float f; } t;
    t.u = ((u32)v) << 16;
    return t.f;
}
// Fast 2^x (raw v_exp_f32; log2e pre-folded into q scale by proj).
static __device__ inline float ex2(float x) {
    float r;
    asm("v_exp_f32 %0, %1" : "=v"(r) : "v"(x));
    return r;
}
// Truncation-pack two floats' high16 bits into one u32: [hi16(b)|hi16(a)].
static __device__ inline u32 packtrunc(float a, float b) {
    return __builtin_amdgcn_perm(__float_as_uint(b), __float_as_uint(a),
                                 0x07060302u);
}

// ---------------- kernel 1: LN stats + normalize + bf16 + transpose --------
__global__ __launch_bounds__(256) void lnxn_kernel(const float* __restrict__ x,
                                                   const float* __restrict__ lnw,
                                                   const float* __restrict__ lnb,
                                                   u16* __restrict__ xnb) {
    int wave = threadIdx.x >> 6, lane = threadIdx.x & 63;
    int n = (blockIdx.x << 2) + wave;
    int r = n >> 9, s = n & (S_ - 1);
    const float4 v = ((const float4*)(x + (size_t)(s * R_ + r) * C_))[lane];
    float sum = v.x + v.y + v.z + v.w;
    float sq = v.x * v.x + v.y * v.y + v.z * v.z + v.w * v.w;
#pragma unroll
    for (int off = 32; off; off >>= 1) {
        sum += __shfl_xor(sum, off);
        sq += __shfl_xor(sq, off);
    }
    float mu = sum * (1.0f / C_);
    float rstd = rsqrtf(sq * (1.0f / C_) - mu * mu + EPS_);
    float4 w4 = ((const float4*)lnw)[lane];
    float4 b4 = ((const float4*)lnb)[lane];
    ushort4 st;
    st.x = f2bf((v.x - mu) * rstd * w4.x + b4.x);
    st.y = f2bf((v.y - mu) * rstd * w4.y + b4.y);
    st.z = f2bf((v.z - mu) * rstd * w4.z + b4.z);
    st.w = f2bf((v.w - mu) * rstd * w4.w + b4.w);
    *(ushort4*)(xnb + (size_t)n * C_ + lane * 4) = st;
}

// ---------------- kernel 2: weights -> bf16, transposed [n][k] -------------
__global__ __launch_bounds__(256) void wcvt_kernel(
    const float* __restrict__ wq, const float* __restrict__ wk,
    const float* __restrict__ wv, const float* __restrict__ wg,
    const float* __restrict__ wf, u16* __restrict__ wcat_t,
    u16* __restrict__ wf_t) {
    __shared__ __align__(16) float tile[32][33];
    const int z = blockIdx.z;
    const float* __restrict__ W =
        (z == 0) ? wq : (z == 1) ? wk : (z == 2) ? wv : (z == 3) ? wg : wf;
    u16* __restrict__ dst = (z < 4) ? (wcat_t + (size_t)z * C_ * C_) : wf_t;
    const int tid = threadIdx.x;
    int rk = tid >> 3, c4 = tid & 7;
    float4 t4 = *(const float4*)&W[(size_t)(blockIdx.x * 32 + rk) * C_ +
                                   blockIdx.y * 32 + c4 * 4];
    tile[rk][c4 * 4 + 0] = t4.x;
    tile[rk][c4 * 4 + 1] = t4.y;
    tile[rk][c4 * 4 + 2] = t4.z;
    tile[rk][c4 * 4 + 3] = t4.w;
    __syncthreads();
    int rn = tid >> 3, k4 = tid & 7;
    ushort4 st;
    st.x = f2bf(tile[k4 * 4 + 0][rn]);
    st.y = f2bf(tile[k4 * 4 + 1][rn]);
    st.z = f2bf(tile[k4 * 4 + 2][rn]);
    st.w = f2bf(tile[k4 * 4 + 3][rn]);
    *(ushort4*)(dst + (size_t)(blockIdx.y * 32 + rn) * C_ + blockIdx.x * 32 +
                k4 * 4) = st;
}

// ---------------- kernel 3: fused q/k/v/g projection GEMM (MFMA) -----------
// 1D grid 4096, XCD-aware decode: the 8 n-tile blocks sharing one A-tile get
// ids congruent mod 8 -> same XCD L2 -> A fetched from HBM once.
__global__ __launch_bounds__(256) void proj_kernel(
    const u16* __restrict__ xnb, const u16* __restrict__ wcat_t,
    const float* __restrict__ bg, u16* __restrict__ qb, u16* __restrict__ kb,
    u16* __restrict__ vb, u16* __restrict__ gb) {
    __shared__ __align__(16) char smem[128 * 272];  // 34816 B
    u16* As = (u16*)smem;             // [128][64] swizzled, 16 KB
    u16* Bs = (u16*)(smem + 16384);   // [128][64] swizzled, 16 KB
    // epilogue reuses smem as Cs[128][136] u16 (pitch 272 B)

    const int tid = threadIdx.x;
    const int l = tid & 63, wid = tid >> 6;
    const int g = l >> 4, ql = l & 15;
    const int wm = wid >> 1, wn = wid & 1;
    // XCD-aware bijective decode (assumes XCD = linear id % 8, perf-only)
    const int id = blockIdx.x;
    const int xcd = id & 7, j = id >> 3;
    const int ntile = j & 7;
    const int mtile = (j >> 3) * 8 + xcd;  // 0..511, all 8 ntiles same xcd
    const int n0 = ntile << 7;
    const int m0 = mtile << 7;
    const int z = ntile >> 1;
    u16* __restrict__ O = (z == 0) ? qb : (z == 1) ? kb : (z == 2) ? vb : gb;

    const f32x4 zz = {0.f, 0.f, 0.f, 0.f};
    f32x4 acc[4][4];
#pragma unroll
    for (int i = 0; i < 4; ++i)
#pragma unroll
        for (int j2 = 0; j2 < 4; ++j2) acc[i][j2] = zz;

    for (int k0 = 0; k0 < C_; k0 += 64) {
        __syncthreads();
#pragma unroll
        for (int rep = 0; rep < 4; ++rep) {
            int idx = tid + rep * 256;
            int row = idx >> 3, c = idx & 7;
            *(uint4*)((char*)As + row * 128 + ((c * 16) ^ ((row & 7) << 4))) =
                *(const uint4*)(xnb + (size_t)(m0 + row) * C_ + k0 + c * 8);
            *(uint4*)((char*)Bs + row * 128 + ((c * 16) ^ ((row & 7) << 4))) =
                *(const uint4*)(wcat_t + (size_t)(n0 + row) * C_ + k0 + c * 8);
        }
        __syncthreads();
#pragma unroll
        for (int ks = 0; ks < 2; ++ks) {
            bf16x8 a[4], b[4];
#pragma unroll
            for (int mf = 0; mf < 4; ++mf) {
                int row = wm * 64 + mf * 16 + ql;
                a[mf] = *(const bf16x8*)((const char*)As + row * 128 +
                                         ((ks * 64 + g * 16) ^ ((row & 7) << 4)));
            }
#pragma unroll
            for (int nf = 0; nf < 4; ++nf) {
                int row = wn * 64 + nf * 16 + ql;
                b[nf] = *(const bf16x8*)((const char*)Bs + row * 128 +
                                         ((ks * 64 + g * 16) ^ ((row & 7) << 4)));
            }
#pragma unroll
            for (int mf = 0; mf < 4; ++mf)
#pragma unroll
                for (int nf = 0; nf < 4; ++nf)
                    acc[mf][nf] = MFMA(a[mf], b[nf], acc[mf][nf]);
        }
    }

    // ---- epilogue: stage into LDS, then coalesced 16B global writes ----
    __syncthreads();  // all As/Bs reads complete before overwrite as Cs
    u16* Cs = (u16*)smem;  // [128][pitch 136]
#pragma unroll
    for (int nf = 0; nf < 4; ++nf) {
        int ncol = wn * 64 + nf * 16 + ql;  // 0..127 in tile
        float bgv = (z == 3) ? bg[(n0 + ncol) & 255] : 0.0f;
#pragma unroll
        for (int mf = 0; mf < 4; ++mf) {
            int mrow = wm * 64 + mf * 16 + g * 4;
#pragma unroll
            for (int i = 0; i < 4; ++i) {
                float v = acc[mf][nf][i];
                // q: 1/sqrt(32) * log2(e) folded (attn uses v_exp = 2^x)
                if (z == 0) v *= 0.25505654003290507f;
                else if (z == 3) v = 1.0f / (1.0f + __expf(-(v + bgv)));
                Cs[(mrow + i) * 136 + ncol] = f2bf(v);
            }
        }
    }
    __syncthreads();
    const int nz0 = (n0 & 255);
#pragma unroll
    for (int rep = 0; rep < 8; ++rep) {
        int idx = tid + rep * 256;
        int row = idx >> 4, c = idx & 15;
        *(uint4*)(O + (size_t)(m0 + row) * C_ + nz0 + c * 8) =
            *(const uint4*)((const char*)Cs + row * 272 + c * 16);
    }
}

// ---------------- kernel 4: attention v4 (MFMA dsum, de-conflicted LDS) ----
// 256 threads / 4 waves per (r,h,half); in-register P; v_exp asm; trunc-pack
// P with dsum via MFMA(ones, P) -> each lane gets its own q-column's exact
// sum of the SAME truncated P (bias cancels; no extraction, no shfl reduce).
// Klds pitch 72B (16-bank kf reads), Vt pitch 152B (4-way transpose writes).
__global__ __launch_bounds__(256) void attn_kernel(
    const u16* __restrict__ qb, const u16* __restrict__ kb,
    const u16* __restrict__ vb, const u16* __restrict__ gb,
    u16* __restrict__ ob) {
    __shared__ __align__(16) u16 Klds[64 * 36];  // [kv][d], pitch 72B
    __shared__ __align__(16) u16 Vt[32 * 76];    // [d][kv], pitch 152B
    const int id = blockIdx.x;
    const int xcd = id & 7, j = id >> 3;
    const int half = j & 1;
    const int rh = (j >> 1) * 8 + xcd;  // 0..1023; both halves same xcd
    const int r = rh >> 3, h = rh & 7;
    const int tid = threadIdx.x;
    const int l = tid & 63, wid = tid >> 6;
    const int g = l >> 4, ql = l & 15;
    const int mbase = r * S_ + half * 256 + wid * 64;
    const int hoff = h * DH_;
    const f32x4 zz = {0.f, 0.f, 0.f, 0.f};
    const bf16x8 onesf = {(short)0x3F80, (short)0x3F80, (short)0x3F80,
                          (short)0x3F80, (short)0x3F80, (short)0x3F80,
                          (short)0x3F80, (short)0x3F80};

    bf16x8 qf[4];
#pragma unroll
    for (int nf = 0; nf < 4; ++nf)
        qf[nf] = *(const bf16x8*)(qb + (size_t)(mbase + nf * 16 + ql) * C_ +
                                  hoff + g * 8);

    f32x4 o[2][4];
    f32x4 dsacc[4];
#pragma unroll
    for (int j2 = 0; j2 < 4; ++j2) {
        o[0][j2] = zz;
        o[1][j2] = zz;
        dsacc[j2] = zz;
    }

    for (int j0 = 0; j0 < S_; j0 += 64) {
        __syncthreads();
        {
            // 256 threads: (kv row, 16B d-chunk). K -> pitch-72 LDS (uint2
            // pairs, 8B aligned); V transposed scalar into pitch-152 Vt.
            int row = tid >> 2, c = tid & 3;
            const size_t gsrc = (size_t)(r * S_ + j0 + row) * C_ + hoff + c * 8;
            uint4 kv4 = *(const uint4*)(kb + gsrc);
            *(uint2*)((char*)Klds + row * 72 + c * 16) = make_uint2(kv4.x, kv4.y);
            *(uint2*)((char*)Klds + row * 72 + c * 16 + 8) =
                make_uint2(kv4.z, kv4.w);
            bf16x8 vv = *(const bf16x8*)(vb + gsrc);
#pragma unroll
            for (int jj = 0; jj < 8; ++jj)
                Vt[(c * 8 + jj) * 76 + row] = (u16)vv[jj];
        }
        __syncthreads();
        bf16x8 kf[4];
#pragma unroll
        for (int mf = 0; mf < 4; ++mf) {
            const char* krow = (const char*)Klds + (mf * 16 + ql) * 72 + g * 16;
            union { bf16x8 v; uint2 u2[2]; } ku;
            ku.u2[0] = *(const uint2*)(krow);
            ku.u2[1] = *(const uint2*)(krow + 8);
            kf[mf] = ku.v;
        }
#pragma unroll
        for (int sub = 0; sub < 2; ++sub) {
            f32x4 s0[4], s1[4];
#pragma unroll
            for (int nf = 0; nf < 4; ++nf) {
                s0[nf] = MFMA(kf[sub * 2 + 0], qf[nf], zz);
                s1[nf] = MFMA(kf[sub * 2 + 1], qf[nf], zz);
            }
            // V^T fragment: k-slots (g,jj): jj<4 -> kv = sub*32+g*4+jj,
            // jj>=4 -> kv = sub*32+16+g*4+(jj-4). Two 8B reads, pitch 152.
            bf16x8 vf[2];
#pragma unroll
            for (int mv = 0; mv < 2; ++mv) {
                const char* vrow = (const char*)Vt + (mv * 16 + ql) * 152;
                union { bf16x8 v; uint2 u2[2]; } vu;
                vu.u2[0] = *(const uint2*)(vrow + (sub * 32 + g * 4) * 2);
                vu.u2[1] = *(const uint2*)(vrow + (sub * 32 + 16 + g * 4) * 2);
                vf[mv] = vu.v;
            }
#pragma unroll
            for (int nf = 0; nf < 4; ++nf) {
                union { bf16x8 v; u32 u[4]; } pu;
                pu.u[0] = packtrunc(ex2(s0[nf][0]), ex2(s0[nf][1]));
                pu.u[1] = packtrunc(ex2(s0[nf][2]), ex2(s0[nf][3]));
                pu.u[2] = packtrunc(ex2(s1[nf][0]), ex2(s1[nf][1]));
                pu.u[3] = packtrunc(ex2(s1[nf][2]), ex2(s1[nf][3]));
                // dsum via ones-MFMA: every C/D row = sum_kv P^T[kv][q];
                // lane (g,ql) gets the sum for its own q-column ql.
                dsacc[nf] = MFMA(onesf, pu.v, dsacc[nf]);
                o[0][nf] = MFMA(vf[0], pu.v, o[0][nf]);
                o[1][nf] = MFMA(vf[1], pu.v, o[1][nf]);
            }
        }
    }

#pragma unroll
    for (int nf = 0; nf < 4; ++nf) {
        float inv = 1.0f / dsacc[nf][0];
        size_t rowoff = (size_t)(mbase + nf * 16 + ql) * C_ + hoff;
#pragma unroll
        for (int mv = 0; mv < 2; ++mv) {
            size_t off = rowoff + mv * 16 + g * 4;
            const ushort4 gv = *(const ushort4*)(gb + off);
            ushort4 st;
            st.x = f2bf(o[mv][nf][0] * inv * bf2f(gv.x));
            st.y = f2bf(o[mv][nf][1] * inv * bf2f(gv.y));
            st.z = f2bf(o[mv][nf][2] * inv * bf2f(gv.z));
            st.w = f2bf(o[mv][nf][3] * inv * bf2f(gv.w));
            *(ushort4*)(ob + off) = st;
        }
    }
}

// ---------------- kernel 5: output projection + bias + transpose -----------
// 1D grid 1024, XCD-aware: both n-tiles sharing an A-tile -> same XCD.
__global__ __launch_bounds__(256) void outproj_kernel(
    const u16* __restrict__ ob, const u16* __restrict__ wf_t,
    const float* __restrict__ bfb, float* __restrict__ out) {
    __shared__ __align__(16) u16 As[128 * 64];
    __shared__ __align__(16) u16 Bs[128 * 64];
    const int tid = threadIdx.x;
    const int l = tid & 63, wid = tid >> 6;
    const int g = l >> 4, ql = l & 15;
    const int wm = wid >> 1, wn = wid & 1;
    const int id = blockIdx.x;
    const int xcd = id & 7, j = id >> 3;
    const int ntile = j & 1;
    const int mtile = (j >> 1) * 8 + xcd;  // 0..511
    const int m0 = mtile << 7;
    const int n0 = ntile << 7;

    const f32x4 zz = {0.f, 0.f, 0.f, 0.f};
    f32x4 acc[4][4];
#pragma unroll
    for (int i = 0; i < 4; ++i)
#pragma unroll
        for (int j2 = 0; j2 < 4; ++j2) acc[i][j2] = zz;

    for (int k0 = 0; k0 < C_; k0 += 64) {
        __syncthreads();
#pragma unroll
        for (int rep = 0; rep < 4; ++rep) {
            int idx = tid + rep * 256;
            int row = idx >> 3, c = idx & 7;
            *(uint4*)((char*)As + row * 128 + ((c * 16) ^ ((row & 7) << 4))) =
                *(const uint4*)(ob + (size_t)(m0 + row) * C_ + k0 + c * 8);
            *(uint4*)((char*)Bs + row * 128 + ((c * 16) ^ ((row & 7) << 4))) =
                *(const uint4*)(wf_t + (size_t)(n0 + row) * C_ + k0 + c * 8);
        }
        __syncthreads();
#pragma unroll
        for (int ks = 0; ks < 2; ++ks) {
            bf16x8 a[4], b[4];
#pragma unroll
            for (int mf = 0; mf < 4; ++mf) {
                int row = wm * 64 + mf * 16 + ql;
                a[mf] = *(const bf16x8*)((const char*)As + row * 128 +
                                         ((ks * 64 + g * 16) ^ ((row & 7) << 4)));
            }
#pragma unroll
            for (int nf = 0; nf < 4; ++nf) {
                int row = wn * 64 + nf * 16 + ql;
                b[nf] = *(const bf16x8*)((const char*)Bs + row * 128 +
                                         ((ks * 64 + g * 16) ^ ((row & 7) << 4)));
            }
#pragma unroll
            for (int mf = 0; mf < 4; ++mf)
#pragma unroll
                for (int nf = 0; nf < 4; ++nf)
                    acc[mf][nf] = MFMA(a[mf], b[nf], acc[mf][nf]);
        }
    }

#pragma unroll
    for (int nf = 0; nf < 4; ++nf) {
        int n_g = n0 + wn * 64 + nf * 16 + ql;
        float bfv = bfb[n_g];
#pragma unroll
        for (int mf = 0; mf < 4; ++mf) {
            int m = m0 + wm * 64 + mf * 16 + g * 4;
#pragma unroll
            for (int i = 0; i < 4; ++i) {
                int mi = m + i;
                int r = mi >> 9, s = mi & (S_ - 1);
                out[(size_t)(s * R_ + r) * C_ + n_g] = acc[mf][nf][i] + bfv;
            }
        }
    }
}

extern "C" void kernel_launch(void* const* d_in, const int* in_sizes, int n_in,
                              void* d_out, int out_size, void* d_ws, size_t ws_size,
                              hipStream_t stream) {
    const float* x = (const float*)d_in[0];
    const float* lnw = (const float*)d_in[1];
    const float* lnb = (const float*)d_in[2];
    const float* wq = (const float*)d_in[3];
    const float* wk = (const float*)d_in[4];
    const float* wv = (const float*)d_in[5];
    const float* wg = (const float*)d_in[6];
    const float* bg = (const float*)d_in[7];
    const float* wf = (const float*)d_in[8];
    const float* bfb = (const float*)d_in[9];
    float* out = (float*)d_out;

    u16* ws = (u16*)d_ws;
    const size_t NC = (size_t)M_ * C_;  // 16,777,216 elems (32 MB as bf16)
    u16* xnb = ws;
    u16* wcat = xnb + NC;
    u16* wft = wcat + 1024 * 256;
    u16* qb = wft + 256 * 256;
    u16* kb = qb + NC;
    u16* vb = kb + NC;
    u16* gb = vb + NC;
    u16* obuf = gb + NC;
    // total: 6*NC + 327680 elems = ~193 MB (ws proven >= that in round 5)

    lnxn_kernel<<<M_ / 4, 256, 0, stream>>>(x, lnw, lnb, xnb);
    wcvt_kernel<<<dim3(8, 8, 5), 256, 0, stream>>>(wq, wk, wv, wg, wf, wcat, wft);
    proj_kernel<<<4096, 256, 0, stream>>>(xnb, wcat, bg, qb, kb, vb, gb);
    attn_kernel<<<2048, 256, 0, stream>>>(qb, kb, vb, gb, obuf);
    outproj_kernel<<<1024, 256, 0, stream>>>(obuf, wft, bfb, out);
}